// Round 1
// baseline (1055.431 us; speedup 1.0000x reference)
//
#include <hip/hip_runtime.h>
#include <hip/hip_bf16.h>
#include <cstdint>
#include <cstddef>

#define N_NODES 50000
#define N_EDGES 800000

// ============================ CSR build ============================

__global__ void hist_kernel(const int* __restrict__ dst, int* __restrict__ deg, int E) {
    int e = blockIdx.x * 256 + threadIdx.x;
    if (e < E) atomicAdd(&deg[dst[e]], 1);
}

// single-block exclusive scan, 1024 elements per iteration (4/thread, wave shuffles)
__global__ void scan_kernel(const int* __restrict__ deg, int* __restrict__ row_ptr,
                            int* __restrict__ cursor, int n) {
    __shared__ int wsum[4];
    __shared__ int s_carry;
    int t = threadIdx.x, lane = t & 63, w = t >> 6;
    if (t == 0) s_carry = 0;
    __syncthreads();
    for (int base = 0; base < n; base += 1024) {
        int idx = base + t * 4;
        int v0 = 0, v1 = 0, v2 = 0, v3 = 0;
        if (idx + 3 < n) {
            int4 d = *(const int4*)(deg + idx);
            v0 = d.x; v1 = d.y; v2 = d.z; v3 = d.w;
        } else {
            if (idx     < n) v0 = deg[idx];
            if (idx + 1 < n) v1 = deg[idx + 1];
            if (idx + 2 < n) v2 = deg[idx + 2];
            if (idx + 3 < n) v3 = deg[idx + 3];
        }
        int tsum = v0 + v1 + v2 + v3;
        int sc = tsum;
        #pragma unroll
        for (int off = 1; off < 64; off <<= 1) {
            int u = __shfl_up(sc, off, 64);
            if (lane >= off) sc += u;
        }
        if (lane == 63) wsum[w] = sc;
        __syncthreads();
        int woff = 0;
        for (int i = 0; i < w; i++) woff += wsum[i];
        int excl = s_carry + woff + sc - tsum;
        if (idx < n)     { row_ptr[idx]     = excl; cursor[idx]     = excl; } excl += v0;
        if (idx + 1 < n) { row_ptr[idx + 1] = excl; cursor[idx + 1] = excl; } excl += v1;
        if (idx + 2 < n) { row_ptr[idx + 2] = excl; cursor[idx + 2] = excl; } excl += v2;
        if (idx + 3 < n) { row_ptr[idx + 3] = excl; cursor[idx + 3] = excl; }
        __syncthreads();
        if (t == 255) s_carry += wsum[0] + wsum[1] + wsum[2] + wsum[3];
        __syncthreads();
    }
    if (t == 0) row_ptr[n] = s_carry;
}

// pack src (16 bits, N<65536) | edge_type<<16
__global__ void fill_kernel(const int* __restrict__ src, const int* __restrict__ dst,
                            const int* __restrict__ et, int* __restrict__ cursor,
                            int* __restrict__ sorted, int E) {
    int e = blockIdx.x * 256 + threadIdx.x;
    if (e < E) {
        int pos = atomicAdd(&cursor[dst[e]], 1);
        sorted[pos] = src[e] | (et[e] << 16);
    }
}

// ============================ Linear 64 -> 128 ============================

__global__ __launch_bounds__(128) void linear_kernel(const float* __restrict__ z,
                                                     const float* __restrict__ w,
                                                     const float* __restrict__ b,
                                                     float* __restrict__ h, int N) {
    int n = blockIdx.x;
    int t = threadIdx.x;
    __shared__ float zs[64];
    if (t < 64) zs[t] = z[(size_t)n * 64 + t];
    __syncthreads();
    const float4* wr4 = (const float4*)(w + (size_t)t * 64);
    float acc = 0.f;
    #pragma unroll
    for (int i = 0; i < 16; i++) {
        float4 v = wr4[i];
        acc = fmaf(zs[i * 4 + 0], v.x, acc);
        acc = fmaf(zs[i * 4 + 1], v.y, acc);
        acc = fmaf(zs[i * 4 + 2], v.z, acc);
        acc = fmaf(zs[i * 4 + 3], v.w, acc);
    }
    h[(size_t)n * 128 + t] = acc + b[t];
}

// ============================ wq = W@q, wk = W@k ============================

__global__ void wqk_kernel(const float* __restrict__ W, const float* __restrict__ q,
                           const float* __restrict__ k, float* __restrict__ wq,
                           float* __restrict__ wk) {
    int g = blockIdx.x * 256 + threadIdx.x;      // 0..2047
    int which = g >> 10;
    int r = (g >> 7) & 7;
    int i = g & 127;
    const float* vec = which ? k : q;
    const float* wrow = W + ((size_t)r * 128 + i) * 128;
    float acc = 0.f;
    #pragma unroll 4
    for (int o = 0; o < 128; o++) acc = fmaf(wrow[o], vec[o], acc);
    (which ? wk : wq)[r * 128 + i] = acc;
}

// ============================ Q[n,r], K[n,r] tables ============================

__global__ __launch_bounds__(256) void qk_table_kernel(const float* __restrict__ x,
                                                       const float* __restrict__ wq,
                                                       const float* __restrict__ wk,
                                                       float* __restrict__ Q,
                                                       float* __restrict__ K, int N) {
    int w = threadIdx.x >> 6, lane = threadIdx.x & 63;
    int n = blockIdx.x * 4 + w;
    if (n >= N) return;
    float x0 = x[(size_t)n * 128 + lane];
    float x1 = x[(size_t)n * 128 + 64 + lane];
    #pragma unroll
    for (int r = 0; r < 8; r++) {
        float pq = x0 * wq[r * 128 + lane] + x1 * wq[r * 128 + 64 + lane];
        float pk = x0 * wk[r * 128 + lane] + x1 * wk[r * 128 + 64 + lane];
        #pragma unroll
        for (int off = 32; off; off >>= 1) {
            pq += __shfl_xor(pq, off, 64);
            pk += __shfl_xor(pk, off, 64);
        }
        if (lane == 0) { Q[(size_t)n * 8 + r] = pq; K[(size_t)n * 8 + r] = pk; }
    }
}

// ============================ x_all = X @ W[r]  (per relation) ============================
// tile: 128 nodes x 128 cols, K=128 in 4 chunks of 32. 256 threads, 8x8 acc each.

__global__ __launch_bounds__(256) void gemm_xall(const float* __restrict__ X,
                                                 const float* __restrict__ W,
                                                 float* __restrict__ Y, int N) {
    int r = blockIdx.y;
    int tile = blockIdx.x;
    const float* Wr = W + (size_t)r * 16384;
    __shared__ float XsT[32][128];   // [k][node]
    __shared__ float Ws[32][128];    // [k][col]
    int t = threadIdx.x;
    int rg = t >> 4;                 // 0..15 -> 8 nodes each
    int cg = t & 15;                 // 0..15 -> 8 cols each
    float acc[8][8] = {};
    int n0 = tile * 128;
    int ln = t >> 1;                 // node this thread stages
    int kh = (t & 1) * 16;           // k-half

    for (int k0 = 0; k0 < 128; k0 += 32) {
        int gn = n0 + ln;
        if (gn < N) {
            const float* xp = X + (size_t)gn * 128 + k0 + kh;
            #pragma unroll
            for (int j = 0; j < 16; j += 4) {
                float4 v = *(const float4*)(xp + j);
                XsT[kh + j + 0][ln] = v.x;
                XsT[kh + j + 1][ln] = v.y;
                XsT[kh + j + 2][ln] = v.z;
                XsT[kh + j + 3][ln] = v.w;
            }
        } else {
            #pragma unroll
            for (int j = 0; j < 16; j++) XsT[kh + j][ln] = 0.f;
        }
        {
            const float* wp = Wr + (size_t)k0 * 128 + t * 16;
            float* wsp = &Ws[0][0] + t * 16;
            #pragma unroll
            for (int j = 0; j < 16; j += 4)
                *(float4*)(wsp + j) = *(const float4*)(wp + j);
        }
        __syncthreads();
        #pragma unroll
        for (int k = 0; k < 32; k++) {
            float a[8], b[8];
            *(float4*)&a[0] = *(const float4*)&XsT[k][rg * 8];
            *(float4*)&a[4] = *(const float4*)&XsT[k][rg * 8 + 4];
            *(float4*)&b[0] = *(const float4*)&Ws[k][cg * 8];
            *(float4*)&b[4] = *(const float4*)&Ws[k][cg * 8 + 4];
            #pragma unroll
            for (int i = 0; i < 8; i++)
                #pragma unroll
                for (int j = 0; j < 8; j++)
                    acc[i][j] = fmaf(a[i], b[j], acc[i][j]);
        }
        __syncthreads();
    }
    #pragma unroll
    for (int i = 0; i < 8; i++) {
        int gn = n0 + rg * 8 + i;
        if (gn < N) {
            float* yp = Y + (size_t)gn * 1024 + r * 128 + cg * 8;
            *(float4*)yp       = *(float4*)&acc[i][0];
            *(float4*)(yp + 4) = *(float4*)&acc[i][4];
        }
    }
}

// ============================ per-dst softmax + aggregate ============================

__global__ __launch_bounds__(128) void agg_kernel(const float* __restrict__ xall,
                                                  const float* __restrict__ Q,
                                                  const float* __restrict__ K,
                                                  const int* __restrict__ row_ptr,
                                                  const int* __restrict__ sorted,
                                                  float* __restrict__ alpha_g,
                                                  const float* __restrict__ bias,
                                                  float* __restrict__ out,
                                                  int relu, int N) {
    int n = blockIdx.x;
    int t = threadIdx.x;
    int beg = row_ptr[n], end = row_ptr[n + 1];
    int deg = end - beg;
    __shared__ float red[128];

    if (deg == 0) {
        float ov = bias[t];
        if (relu) ov = fmaxf(ov, 0.f);
        out[(size_t)n * 128 + t] = ov;
        return;
    }

    // pass 1: alpha + running max
    float lmax = -INFINITY;
    for (int j = t; j < deg; j += 128) {
        int pk = sorted[beg + j];
        int src = pk & 0xFFFF;
        int et = pk >> 16;
        float a = Q[(size_t)n * 8 + et] + K[(size_t)src * 8 + et];
        a = (a > 0.f) ? a : 0.2f * a;                    // leaky_relu 0.2
        alpha_g[beg + j] = a;
        lmax = fmaxf(lmax, a);
    }
    red[t] = lmax;
    __syncthreads();
    #pragma unroll
    for (int off = 64; off; off >>= 1) {
        if (t < off) red[t] = fmaxf(red[t], red[t + off]);
        __syncthreads();
    }
    float m = red[0];
    __syncthreads();

    // denom
    float lsum = 0.f;
    for (int j = t; j < deg; j += 128) lsum += __expf(alpha_g[beg + j] - m);
    red[t] = lsum;
    __syncthreads();
    #pragma unroll
    for (int off = 64; off; off >>= 1) {
        if (t < off) red[t] += red[t + off];
        __syncthreads();
    }
    float inv = 1.f / (red[0] + 1e-16f);

    // pass 2: weighted sum of x_all rows
    float acc = 0.f;
    for (int j = 0; j < deg; j++) {
        int pk = sorted[beg + j];
        int src = pk & 0xFFFF;
        int et = pk >> 16;
        float wgt = __expf(alpha_g[beg + j] - m) * inv;
        acc = fmaf(wgt, xall[(size_t)src * 1024 + et * 128 + t], acc);
    }
    float ov = acc + bias[t];
    if (relu) ov = fmaxf(ov, 0.f);
    out[(size_t)n * 128 + t] = ov;
}

// ============================ launch ============================

extern "C" void kernel_launch(void* const* d_in, const int* in_sizes, int n_in,
                              void* d_out, int out_size, void* d_ws, size_t ws_size,
                              hipStream_t stream) {
    const float* z     = (const float*)d_in[0];
    const float* lin_w = (const float*)d_in[1];
    const float* lin_b = (const float*)d_in[2];
    const float* w1    = (const float*)d_in[3];
    const float* q1    = (const float*)d_in[4];
    const float* k1    = (const float*)d_in[5];
    const float* b1    = (const float*)d_in[6];
    const float* w2    = (const float*)d_in[7];
    const float* q2    = (const float*)d_in[8];
    const float* k2    = (const float*)d_in[9];
    const float* b2    = (const float*)d_in[10];
    const int*   ei    = (const int*)d_in[11];
    const int*   et    = (const int*)d_in[12];
    float* out = (float*)d_out;

    char* ws = (char*)d_ws;
    size_t off = 0;
    auto alloc = [&](size_t bytes) -> void* {
        void* p = ws + off;
        off += (bytes + 255) & ~(size_t)255;
        return p;
    };
    float* xall  = (float*)alloc((size_t)N_NODES * 1024 * 4);   // 204.8 MB
    float* h     = (float*)alloc((size_t)N_NODES * 128 * 4);    // 25.6 MB (reused as layer1 out)
    float* Q     = (float*)alloc((size_t)N_NODES * 8 * 4);
    float* K     = (float*)alloc((size_t)N_NODES * 8 * 4);
    float* alpha = (float*)alloc((size_t)N_EDGES * 4);
    int* sorted  = (int*)alloc((size_t)N_EDGES * 4);
    int* deg     = (int*)alloc((size_t)N_NODES * 4);
    int* rowp    = (int*)alloc((size_t)(N_NODES + 1) * 4);
    int* cursor  = (int*)alloc((size_t)N_NODES * 4);
    float* wq    = (float*)alloc(8 * 128 * 4);
    float* wk    = (float*)alloc(8 * 128 * 4);

    const int* src = ei;
    const int* dst = ei + N_EDGES;

    // CSR build (graph fixed per launch, rebuilt every call: ws is re-poisoned)
    hipMemsetAsync(deg, 0, (size_t)N_NODES * 4, stream);
    hist_kernel<<<(N_EDGES + 255) / 256, 256, 0, stream>>>(dst, deg, N_EDGES);
    scan_kernel<<<1, 256, 0, stream>>>(deg, rowp, cursor, N_NODES);
    fill_kernel<<<(N_EDGES + 255) / 256, 256, 0, stream>>>(src, dst, et, cursor, sorted, N_EDGES);

    // h = z @ lin_w.T + lin_b
    linear_kernel<<<N_NODES, 128, 0, stream>>>(z, lin_w, lin_b, h, N_NODES);

    dim3 ggrid((N_NODES + 127) / 128, 8);

    // ---- layer 1 (relu) : h -> h
    wqk_kernel<<<8, 256, 0, stream>>>(w1, q1, k1, wq, wk);
    qk_table_kernel<<<(N_NODES + 3) / 4, 256, 0, stream>>>(h, wq, wk, Q, K, N_NODES);
    gemm_xall<<<ggrid, 256, 0, stream>>>(h, w1, xall, N_NODES);
    agg_kernel<<<N_NODES, 128, 0, stream>>>(xall, Q, K, rowp, sorted, alpha, b1, h, 1, N_NODES);

    // ---- layer 2 (no relu) : h -> out
    wqk_kernel<<<8, 256, 0, stream>>>(w2, q2, k2, wq, wk);
    qk_table_kernel<<<(N_NODES + 3) / 4, 256, 0, stream>>>(h, wq, wk, Q, K, N_NODES);
    gemm_xall<<<ggrid, 256, 0, stream>>>(h, w2, xall, N_NODES);
    agg_kernel<<<N_NODES, 128, 0, stream>>>(xall, Q, K, rowp, sorted, alpha, b2, out, 0, N_NODES);
}